// Round 1
// baseline (1225.925 us; speedup 1.0000x reference)
//
#include <hip/hip_runtime.h>

// rmsdLoss: B=2048 rows, L=4087 values/row -> two 1024x3 chains per row,
// output = mean((pred_coords - targ_coords)^2), single fp32 scalar.
//
// ws layout (floats):
//   clA : NSTEP*NCH            (-l*cos(theta))
//   mlA : NSTEP*NCH            ( l*sin(theta)*cos(chi))
//   nlA : NSTEP*NCH            ( l*sin(theta)*sin(chi))
//   initA : NCH float4         (bl0, a2.x, a2.y, 0)
// total = 3*1021*4096*4 + 4096*16 = 50,249,728 bytes (~48 MiB)

#define LROW  4087
#define NSTEP 1021
#define NCH   4096
#define NROW  2048
#define EPSF  1e-6f

__device__ __forceinline__ float frcp(float x) { return __builtin_amdgcn_rcpf(x); }
__device__ __forceinline__ float clip1(float x) { return fminf(fmaxf(x, -1.0f), 1.0f); }

__global__ void coef_kernel(const float* __restrict__ pred,
                            const float* __restrict__ targ,
                            float* __restrict__ clA,
                            float* __restrict__ mlA,
                            float* __restrict__ nlA,
                            float4* __restrict__ initA) {
    const int c   = blockIdx.x * blockDim.x + threadIdx.x;  // chain 0..4095
    const int j   = blockIdx.y;                             // step 0..1020
    const int row = c >> 1;
    const bool isPred = (c & 1) == 0;
    const float* __restrict__ v = (isPred ? pred : targ) + (size_t)row * LROW;

    // raw loads for step j: chi[j] needs sc pair, theta[1+j] needs d13[1+j], bl[1+j], bl[2+j]
    float sc0 = v[2 * j];
    float sc1 = v[2 * j + 1];
    float rd  = v[2043 + j];   // d13[1+j] raw
    float rb1 = v[3065 + j];   // bl[1+j] raw
    float rb2 = v[3066 + j];   // bl[2+j] raw
    if (isPred) {
        sc0 = clip1(sc0); sc1 = clip1(sc1);
        rd = clip1(rd); rb1 = clip1(rb1); rb2 = clip1(rb2);
    }
    // denorm: d13: (x+1)*0.5*3.5+1.5 = 1.75x+3.25 ; bl: (x+1)*0.5*2.1+0.9 = 1.05x+1.95
    const float d13 = fmaf(rd, 1.75f, 3.25f);
    const float b1  = fmaf(rb1, 1.05f, 1.95f);
    const float b2  = fmaf(rb2, 1.05f, 1.95f);

    // cos(theta) via law of cosines; sin(theta) = sqrt(1-ct^2) (theta in [0,pi])
    float ct = (b1 * b1 + b2 * b2 - d13 * d13) * frcp(2.0f * b1 * b2);
    ct = fminf(fmaxf(ct, -1.0f + EPSF), 1.0f - EPSF);
    const float st = sqrtf(fmaxf(1.0f - ct * ct, 0.0f));

    // chi = atan2(sc0, sc1): sin = sc0/r, cos = sc1/r
    const float r2 = sc0 * sc0 + sc1 * sc1;
    const bool ok = (r2 > 1e-36f);
    const float ir = ok ? frcp(sqrtf(r2)) : 0.0f;
    const float sch = sc0 * ir;
    const float cch = ok ? sc1 * ir : 1.0f;

    const float l = b2;  // bl[2+j]
    const size_t idx = (size_t)j * NCH + c;
    clA[idx] = -l * ct;
    mlA[idx] = l * st * cch;
    nlA[idx] = l * st * sch;

    if (j == 0) {
        // init: theta[0] from bl[0], bl[1], d13[0]; a1=(bl0,0,0); a2=a1+bl1*(-ct0, st0, 0)
        float rb0 = v[3064];
        float rd0 = v[2042];
        if (isPred) { rb0 = clip1(rb0); rd0 = clip1(rd0); }
        const float bl0 = fmaf(rb0, 1.05f, 1.95f);
        const float d0  = fmaf(rd0, 1.75f, 3.25f);
        float ct0 = (bl0 * bl0 + b1 * b1 - d0 * d0) * frcp(2.0f * bl0 * b1);
        ct0 = fminf(fmaxf(ct0, -1.0f + EPSF), 1.0f - EPSF);
        const float st0 = sqrtf(fmaxf(1.0f - ct0 * ct0, 0.0f));
        initA[c] = make_float4(bl0, bl0 - b1 * ct0, b1 * st0, 0.0f);
    }
}

struct Chain { float ax, ay, az, bx, by, bz, cx, cy, cz; };

__device__ __forceinline__ void step_chain(Chain& s, float cl, float ml, float nl) {
    // bc = normalize(c-b) with +EPS (reference semantics)
    float bcx = s.cx - s.bx, bcy = s.cy - s.by, bcz = s.cz - s.bz;
    const float inv = frcp(sqrtf(bcx * bcx + bcy * bcy + bcz * bcz) + EPSF);
    bcx *= inv; bcy *= inv; bcz *= inv;
    // n = normalize(cross(b-a, bc))
    const float bax = s.bx - s.ax, bay = s.by - s.ay, baz = s.bz - s.az;
    float nx = bay * bcz - baz * bcy;
    float ny = baz * bcx - bax * bcz;
    float nz = bax * bcy - bay * bcx;
    const float invn = frcp(sqrtf(nx * nx + ny * ny + nz * nz) + EPSF);
    nx *= invn; ny *= invn; nz *= invn;
    // m = cross(n, bc)
    const float mx = ny * bcz - nz * bcy;
    const float my = nz * bcx - nx * bcz;
    const float mz = nx * bcy - ny * bcx;
    // d = c + cl*bc + ml*m + nl*n
    const float dx = s.cx + cl * bcx + ml * mx + nl * nx;
    const float dy = s.cy + cl * bcy + ml * my + nl * ny;
    const float dz = s.cz + cl * bcz + ml * mz + nl * nz;
    s.ax = s.bx; s.ay = s.by; s.az = s.bz;
    s.bx = s.cx; s.by = s.cy; s.bz = s.cz;
    s.cx = dx;   s.cy = dy;   s.cz = dz;
}

__global__ void __launch_bounds__(64)
chain_kernel(const float* __restrict__ clA, const float* __restrict__ mlA,
             const float* __restrict__ nlA, const float4* __restrict__ initA,
             float* __restrict__ out) {
    const int r  = blockIdx.x * 64 + threadIdx.x;  // row 0..2047
    const int c0 = 2 * r;                           // pred chain; c0+1 = targ chain

    const float4 i0 = initA[c0];
    const float4 i1 = initA[c0 + 1];

    float acc = 0.0f;
    {   // a0 diff = 0; a1 = (bl0,0,0); a2 = (i.y, i.z, 0)
        float d;
        d = i0.x - i1.x; acc += d * d;
        d = i0.y - i1.y; acc += d * d;
        d = i0.z - i1.z; acc += d * d;
    }

    Chain s0 = {0.f, 0.f, 0.f, i0.x, 0.f, 0.f, i0.y, i0.z, 0.f};
    Chain s1 = {0.f, 0.f, 0.f, i1.x, 0.f, 0.f, i1.y, i1.z, 0.f};

    const float2* __restrict__ clP = (const float2*)clA;  // [j][NCH/2] of (pred,targ)
    const float2* __restrict__ mlP = (const float2*)mlA;
    const float2* __restrict__ nlP = (const float2*)nlA;

    float2 cl = clP[r], ml = mlP[r], nl = nlP[r];
    for (int j = 0; j < NSTEP; ++j) {
        const int jn = (j + 1 < NSTEP) ? (j + 1) : j;
        const size_t idx2 = (size_t)jn * (NCH / 2) + r;
        const float2 cln = clP[idx2];
        const float2 mln = mlP[idx2];
        const float2 nln = nlP[idx2];

        step_chain(s0, cl.x, ml.x, nl.x);
        step_chain(s1, cl.y, ml.y, nl.y);
        const float dx = s0.cx - s1.cx;
        const float dy = s0.cy - s1.cy;
        const float dz = s0.cz - s1.cz;
        acc = fmaf(dx, dx, acc);
        acc = fmaf(dy, dy, acc);
        acc = fmaf(dz, dz, acc);

        cl = cln; ml = mln; nl = nln;
    }

    #pragma unroll
    for (int off = 32; off > 0; off >>= 1) acc += __shfl_down(acc, off);
    if (threadIdx.x == 0) {
        atomicAdd(out, acc * (1.0f / (2048.0f * 1024.0f * 3.0f)));
    }
}

extern "C" void kernel_launch(void* const* d_in, const int* in_sizes, int n_in,
                              void* d_out, int out_size, void* d_ws, size_t ws_size,
                              hipStream_t stream) {
    const float* pred = (const float*)d_in[0];
    const float* targ = (const float*)d_in[1];
    float* out = (float*)d_out;

    const size_t S = (size_t)NSTEP * NCH;
    float*  clA   = (float*)d_ws;
    float*  mlA   = clA + S;
    float*  nlA   = mlA + S;
    float4* initA = (float4*)(nlA + S);  // offset 3S*4 bytes, 16B-aligned

    hipMemsetAsync(d_out, 0, sizeof(float), stream);

    dim3 g1(NCH / 256, NSTEP);
    coef_kernel<<<g1, 256, 0, stream>>>(pred, targ, clA, mlA, nlA, initA);
    chain_kernel<<<NROW / 64, 64, 0, stream>>>(clA, mlA, nlA, initA, out);
}

// Round 2
// 204.877 us; speedup vs baseline: 5.9837x; 5.9837x over previous
//
#include <hip/hip_runtime.h>

// rmsdLoss via associative affine scan.
// Per row: two chains (pred clipped, targ). Step j (j=0..1020) is the rigid map
//   p -> p + F*w_j ; F -> F*R_j
// with w_j = (-l ct, l st cc, l st sc), l = bl[2+j], theta from law of cosines,
// chi from atan2(sc0, sc1)  (sc = sin/cos components; sc=sin, cc=cos below).
// R_j columns: [ w_hat | (-st, -ct*cc, -ct*sc) | (0, -sc, cc) ].
// Chunk elements (M,t) combine as (Ma*Mb, ta + Ma*tb). Positions:
//   d_j = a2 + F0 * (prefix t through step j),  F0 from (a0,a1,a2).

#define LROW  4087
#define NSTEP 1021
#define NROW  2048
#define EPSF  1e-6f
#define INVMEAN (1.0f / (2048.0f * 1024.0f * 3.0f))

__device__ __forceinline__ float frcp(float x){ return __builtin_amdgcn_rcpf(x); }
__device__ __forceinline__ float clip1(float x){ return fminf(fmaxf(x,-1.0f),1.0f); }

struct Xf { float f[12]; };  // f[0..8] = M row-major, f[9..11] = t

__device__ __forceinline__ Xf xident(){
  Xf X;
  X.f[0]=1.f; X.f[1]=0.f; X.f[2]=0.f;
  X.f[3]=0.f; X.f[4]=1.f; X.f[5]=0.f;
  X.f[6]=0.f; X.f[7]=0.f; X.f[8]=1.f;
  X.f[9]=0.f; X.f[10]=0.f; X.f[11]=0.f;
  return X;
}

// A applied first, then B:  (Ma*Mb, ta + Ma*tb)
__device__ __forceinline__ Xf xcombine(const Xf& A, const Xf& B){
  Xf C;
  #pragma unroll
  for (int r = 0; r < 3; ++r){
    const float a0 = A.f[3*r], a1 = A.f[3*r+1], a2 = A.f[3*r+2];
    C.f[3*r]   = a0*B.f[0] + a1*B.f[3] + a2*B.f[6];
    C.f[3*r+1] = a0*B.f[1] + a1*B.f[4] + a2*B.f[7];
    C.f[3*r+2] = a0*B.f[2] + a1*B.f[5] + a2*B.f[8];
    C.f[9+r]   = A.f[9+r] + a0*B.f[9] + a1*B.f[10] + a2*B.f[11];
  }
  return C;
}

struct Coef { float wx, wy, wz, il, ct, st, cc, sc; };

// running (M,t) <- combine(running, step): t += M*w ; M <- M*R
__device__ __forceinline__ void xstep(Xf& X, const Coef& k){
  const float ux = X.f[0]*k.wx + X.f[1]*k.wy + X.f[2]*k.wz;
  const float uy = X.f[3]*k.wx + X.f[4]*k.wy + X.f[5]*k.wz;
  const float uz = X.f[6]*k.wx + X.f[7]*k.wy + X.f[8]*k.wz;
  X.f[9] += ux; X.f[10] += uy; X.f[11] += uz;
  const float a = -k.st, b = -k.ct*k.cc, d = -k.ct*k.sc;
  const float n1x = a*X.f[0] + b*X.f[1] + d*X.f[2];
  const float n1y = a*X.f[3] + b*X.f[4] + d*X.f[5];
  const float n1z = a*X.f[6] + b*X.f[7] + d*X.f[8];
  const float n2x = -k.sc*X.f[1] + k.cc*X.f[2];
  const float n2y = -k.sc*X.f[4] + k.cc*X.f[5];
  const float n2z = -k.sc*X.f[7] + k.cc*X.f[8];
  X.f[0] = ux*k.il; X.f[1] = n1x; X.f[2] = n2x;
  X.f[3] = uy*k.il; X.f[4] = n1y; X.f[5] = n2y;
  X.f[6] = uz*k.il; X.f[7] = n1z; X.f[8] = n2z;
}

__global__ void __launch_bounds__(256)
rmsd_kernel(const float* __restrict__ pred, const float* __restrict__ targ,
            float* __restrict__ out){
  __shared__ float sA[2][1024];   // sc0[j]
  __shared__ float sB[2][1024];   // sc1[j]
  __shared__ float dd[2][1024];   // raw d13[1+j]
  __shared__ float bb[2][1024];   // raw bl[1+j]  (j=0..1021)
  __shared__ float xch[2][4][12]; // per-wave scan totals
  __shared__ float ir2[2][2];     // [c][0]=raw bl[0], [c][1]=raw d13[0]

  const int row = blockIdx.x;
  const int tid = threadIdx.x;
  const int ln  = tid & 63;
  const int wv  = tid >> 6;

  const float* __restrict__ vp = pred + (size_t)row * LROW;
  const float* __restrict__ vt = targ + (size_t)row * LROW;

  // ---- stage raw rows into LDS (coalesced), clip pred here ----
  for (int i = tid; i < LROW; i += 256){
    const float xp = clip1(vp[i]);
    const float xt = vt[i];
    if (i < 2042){
      const int j = i >> 1;
      if (i & 1){ sB[0][j] = xp; sB[1][j] = xt; }
      else      { sA[0][j] = xp; sA[1][j] = xt; }
    } else if (i == 2042){ ir2[0][1] = xp; ir2[1][1] = xt; }
    else if (i < 3064){ const int j = i - 2043; dd[0][j] = xp; dd[1][j] = xt; }
    else if (i == 3064){ ir2[0][0] = xp; ir2[1][0] = xt; }
    else { const int j = i - 3065; bb[0][j] = xp; bb[1][j] = xt; }
  }
  __syncthreads();

  auto coef = [&](int c, int j) -> Coef {
    Coef K;
    const float s0 = sA[c][j], s1 = sB[c][j];
    const float d  = fmaf(dd[c][j],   1.75f, 3.25f);
    const float b1 = fmaf(bb[c][j],   1.05f, 1.95f);
    const float b2 = fmaf(bb[c][j+1], 1.05f, 1.95f);
    float ct = (b1*b1 + b2*b2 - d*d) * frcp(2.0f*b1*b2);
    ct = fminf(fmaxf(ct, -1.0f + EPSF), 1.0f - EPSF);
    const float st = sqrtf(fmaxf(1.0f - ct*ct, 0.0f));
    const float r2 = s0*s0 + s1*s1;
    const bool ok = r2 > 1e-36f;
    const float ir = ok ? frcp(sqrtf(r2)) : 0.0f;
    K.sc = s0 * ir;
    K.cc = ok ? s1 * ir : 1.0f;
    K.ct = ct; K.st = st;
    K.il = frcp(b2);
    const float lst = b2 * st;
    K.wx = -b2*ct; K.wy = lst*K.cc; K.wz = lst*K.sc;
    return K;
  };

  // ---- phase 1: per-lane chunk compose (4 steps, both chains) ----
  Xf inc[2] = { xident(), xident() };
  const int j0 = tid * 4;
  #pragma unroll
  for (int k = 0; k < 4; ++k){
    const int j = j0 + k;
    if (j < NSTEP){
      xstep(inc[0], coef(0, j));
      xstep(inc[1], coef(1, j));
    }
  }

  // ---- wave-level inclusive scan (Hillis-Steele, non-commutative) ----
  #pragma unroll
  for (int off = 1; off < 64; off <<= 1){
    Xf o[2];
    #pragma unroll
    for (int c = 0; c < 2; ++c)
      #pragma unroll
      for (int i = 0; i < 12; ++i) o[c].f[i] = __shfl_up(inc[c].f[i], off);
    if (ln >= off){
      inc[0] = xcombine(o[0], inc[0]);
      inc[1] = xcombine(o[1], inc[1]);
    }
  }
  if (ln == 63){
    #pragma unroll
    for (int c = 0; c < 2; ++c)
      #pragma unroll
      for (int i = 0; i < 12; ++i) xch[c][wv][i] = inc[c].f[i];
  }
  Xf ex[2];
  #pragma unroll
  for (int c = 0; c < 2; ++c)
    #pragma unroll
    for (int i = 0; i < 12; ++i) ex[c].f[i] = __shfl_up(inc[c].f[i], 1);
  if (ln == 0){ ex[0] = xident(); ex[1] = xident(); }
  __syncthreads();

  // ---- inter-wave exclusive prefix ----
  Xf E[2];
  #pragma unroll
  for (int c = 0; c < 2; ++c){
    if (wv == 0){ E[c] = ex[c]; }
    else {
      Xf P;
      #pragma unroll
      for (int i = 0; i < 12; ++i) P.f[i] = xch[c][0][i];
      for (int w2 = 1; w2 < wv; ++w2){
        Xf Q;
        #pragma unroll
        for (int i = 0; i < 12; ++i) Q.f[i] = xch[c][w2][i];
        P = xcombine(P, Q);
      }
      E[c] = xcombine(P, ex[c]);
    }
  }

  // ---- phase 3: fold (F0, a2) into prefix, replay chunk, accumulate diff^2 ----
  float acc = 0.0f;
  Xf R3[2];
  float a1x[2], a2x[2], a2y[2];
  #pragma unroll
  for (int c = 0; c < 2; ++c){
    const float bl0 = fmaf(ir2[c][0], 1.05f, 1.95f);
    const float d0  = fmaf(ir2[c][1], 1.75f, 3.25f);
    const float b1  = fmaf(bb[c][0],  1.05f, 1.95f);
    float ct0 = (bl0*bl0 + b1*b1 - d0*d0) * frcp(2.0f*bl0*b1);
    ct0 = fminf(fmaxf(ct0, -1.0f + EPSF), 1.0f - EPSF);
    const float st0 = sqrtf(fmaxf(1.0f - ct0*ct0, 0.0f));
    a1x[c] = bl0;
    a2x[c] = bl0 - b1*ct0;
    a2y[c] = b1*st0;
    // G = F0 * E.M ; q = a2 + F0 * E.t   (F0 rows: (-ct0,-st0,0),(st0,-ct0,0),(0,0,1))
    const Xf& Ec = E[c];
    Xf G;
    G.f[0] = -ct0*Ec.f[0] - st0*Ec.f[3];
    G.f[1] = -ct0*Ec.f[1] - st0*Ec.f[4];
    G.f[2] = -ct0*Ec.f[2] - st0*Ec.f[5];
    G.f[3] =  st0*Ec.f[0] - ct0*Ec.f[3];
    G.f[4] =  st0*Ec.f[1] - ct0*Ec.f[4];
    G.f[5] =  st0*Ec.f[2] - ct0*Ec.f[5];
    G.f[6] = Ec.f[6]; G.f[7] = Ec.f[7]; G.f[8] = Ec.f[8];
    G.f[9]  = a2x[c] - ct0*Ec.f[9] - st0*Ec.f[10];
    G.f[10] = a2y[c] + st0*Ec.f[9] - ct0*Ec.f[10];
    G.f[11] = Ec.f[11];
    R3[c] = G;
  }
  if (tid == 0){
    const float dx = a1x[0] - a1x[1];   // a1 differs only in x
    const float dy = a2x[0] - a2x[1];
    const float dz = a2y[0] - a2y[1];   // a2 differs in x,y (z=0); a0 diff = 0
    acc = dx*dx + dy*dy + dz*dz;
  }

  #pragma unroll
  for (int k = 0; k < 4; ++k){
    const int j = j0 + k;
    if (j < NSTEP){
      xstep(R3[0], coef(0, j));
      xstep(R3[1], coef(1, j));
      const float dx = R3[0].f[9]  - R3[1].f[9];
      const float dy = R3[0].f[10] - R3[1].f[10];
      const float dz = R3[0].f[11] - R3[1].f[11];
      acc = fmaf(dx, dx, acc);
      acc = fmaf(dy, dy, acc);
      acc = fmaf(dz, dz, acc);
    }
  }

  // ---- reduce + atomic ----
  #pragma unroll
  for (int off = 32; off > 0; off >>= 1) acc += __shfl_down(acc, off);
  if (ln == 0) atomicAdd(out, acc * INVMEAN);
}

extern "C" void kernel_launch(void* const* d_in, const int* in_sizes, int n_in,
                              void* d_out, int out_size, void* d_ws, size_t ws_size,
                              hipStream_t stream) {
  const float* pred = (const float*)d_in[0];
  const float* targ = (const float*)d_in[1];
  float* out = (float*)d_out;

  hipMemsetAsync(d_out, 0, sizeof(float), stream);
  rmsd_kernel<<<NROW, 256, 0, stream>>>(pred, targ, out);
}

// Round 3
// 198.367 us; speedup vs baseline: 6.1801x; 1.0328x over previous
//
#include <hip/hip_runtime.h>

// rmsdLoss via associative affine scan, register-resident coefficients.
// Step j (j=0..1020) is the rigid map  p -> p + F*w_j ; F -> F*R_j  with
//   w_j = (-l ct, l st cc, l st sc), l = bl[2+j],
//   R_j columns: [ w_hat | (-st, -ct*cc, -ct*sc) | (0, -sc, cc) ]   (= Rx(chi)*Rz(pi-theta))
// Chunk elements (M,t) combine as (Ma*Mb, ta + Ma*tb).
// Lane t owns steps [4t, 4t+4); phase 1 composes the chunk saving local-prefix
// translations; a 6-level shuffle scan + tiny inter-wave scan gives the
// exclusive prefix E; positions are d_k = G.t + G.M * t_local(k) with
// G = fold(F0, a2, E). No LDS staging -> no bank conflicts.

#define LROW  4087
#define NSTEP 1021
#define NROW  2048
#define EPSF  1e-6f
#define INVMEAN (1.0f / (2048.0f * 1024.0f * 3.0f))

__device__ __forceinline__ float frcp(float x){ return __builtin_amdgcn_rcpf(x); }
__device__ __forceinline__ float clip1(float x){ return fminf(fmaxf(x,-1.0f),1.0f); }

struct Xf { float f[12]; };  // f[0..8] = M row-major, f[9..11] = t

__device__ __forceinline__ Xf xident(){
  Xf X;
  X.f[0]=1.f; X.f[1]=0.f; X.f[2]=0.f;
  X.f[3]=0.f; X.f[4]=1.f; X.f[5]=0.f;
  X.f[6]=0.f; X.f[7]=0.f; X.f[8]=1.f;
  X.f[9]=0.f; X.f[10]=0.f; X.f[11]=0.f;
  return X;
}

// A applied first, then B:  (Ma*Mb, ta + Ma*tb)
__device__ __forceinline__ Xf xcombine(const Xf& A, const Xf& B){
  Xf C;
  #pragma unroll
  for (int r = 0; r < 3; ++r){
    const float a0 = A.f[3*r], a1 = A.f[3*r+1], a2 = A.f[3*r+2];
    C.f[3*r]   = a0*B.f[0] + a1*B.f[3] + a2*B.f[6];
    C.f[3*r+1] = a0*B.f[1] + a1*B.f[4] + a2*B.f[7];
    C.f[3*r+2] = a0*B.f[2] + a1*B.f[5] + a2*B.f[8];
    C.f[9+r]   = A.f[9+r] + a0*B.f[9] + a1*B.f[10] + a2*B.f[11];
  }
  return C;
}

struct Coef { float wx, wy, wz, il, ct, st, cc, sc; };

// running (M,t) <- combine(running, step): t += M*w ; M <- M*R
__device__ __forceinline__ void xstep(Xf& X, const Coef& k){
  const float ux = X.f[0]*k.wx + X.f[1]*k.wy + X.f[2]*k.wz;
  const float uy = X.f[3]*k.wx + X.f[4]*k.wy + X.f[5]*k.wz;
  const float uz = X.f[6]*k.wx + X.f[7]*k.wy + X.f[8]*k.wz;
  X.f[9] += ux; X.f[10] += uy; X.f[11] += uz;
  const float a = -k.st, b = -k.ct*k.cc, d = -k.ct*k.sc;
  const float n1x = a*X.f[0] + b*X.f[1] + d*X.f[2];
  const float n1y = a*X.f[3] + b*X.f[4] + d*X.f[5];
  const float n1z = a*X.f[6] + b*X.f[7] + d*X.f[8];
  const float n2x = -k.sc*X.f[1] + k.cc*X.f[2];
  const float n2y = -k.sc*X.f[4] + k.cc*X.f[5];
  const float n2z = -k.sc*X.f[7] + k.cc*X.f[8];
  X.f[0] = ux*k.il; X.f[1] = n1x; X.f[2] = n2x;
  X.f[3] = uy*k.il; X.f[4] = n1y; X.f[5] = n2y;
  X.f[6] = uz*k.il; X.f[7] = n1z; X.f[8] = n2z;
}

// X = first step directly (identity composed with step)
__device__ __forceinline__ void xinit(Xf& X, const Coef& k){
  X.f[0] = -k.ct;      X.f[1] = -k.st;      X.f[2] = 0.f;
  X.f[3] = k.st*k.cc;  X.f[4] = -k.ct*k.cc; X.f[5] = -k.sc;
  X.f[6] = k.st*k.sc;  X.f[7] = -k.ct*k.sc; X.f[8] = k.cc;
  X.f[9] = k.wx;       X.f[10] = k.wy;      X.f[11] = k.wz;
}

__device__ __forceinline__ Coef mkcoef(const float* __restrict__ v, int j, bool doclip){
  float s0  = v[2*j];
  float s1  = v[2*j+1];
  float rd  = v[2043 + j];   // d13[1+j] raw
  float rb1 = v[3065 + j];   // bl[1+j] raw
  float rb2 = v[3066 + j];   // bl[2+j] raw
  if (doclip){
    s0 = clip1(s0); s1 = clip1(s1);
    rd = clip1(rd); rb1 = clip1(rb1); rb2 = clip1(rb2);
  }
  const float d  = fmaf(rd,  1.75f, 3.25f);
  const float b1 = fmaf(rb1, 1.05f, 1.95f);
  const float b2 = fmaf(rb2, 1.05f, 1.95f);
  float ct = (b1*b1 + b2*b2 - d*d) * frcp(2.0f*b1*b2);
  ct = fminf(fmaxf(ct, -1.0f + EPSF), 1.0f - EPSF);
  const float st = sqrtf(fmaxf(1.0f - ct*ct, 0.0f));
  const float r2 = s0*s0 + s1*s1;
  const bool ok = r2 > 1e-36f;
  const float ir = ok ? frcp(sqrtf(r2)) : 0.0f;
  Coef K;
  K.sc = s0 * ir;
  K.cc = ok ? s1 * ir : 1.0f;
  K.ct = ct; K.st = st;
  K.il = frcp(b2);
  const float lst = b2 * st;
  K.wx = -b2*ct; K.wy = lst*K.cc; K.wz = lst*K.sc;
  return K;
}

__global__ void __launch_bounds__(256)
rmsd_kernel(const float* __restrict__ pred, const float* __restrict__ targ,
            float* __restrict__ out){
  __shared__ float xch[2][4][12]; // per-wave scan totals (384 B)

  const int row = blockIdx.x;
  const int tid = threadIdx.x;
  const int ln  = tid & 63;
  const int wv  = tid >> 6;
  const int j0  = tid * 4;

  const float* __restrict__ vp = pred + (size_t)row * LROW;
  const float* __restrict__ vt = targ + (size_t)row * LROW;
  const float* vb[2] = { vp, vt };

  // ---- phase 1: per-lane chunk compose, snapshot local-prefix translations ----
  Xf inc[2];
  float tl[2][4][3];
  #pragma unroll
  for (int c = 0; c < 2; ++c){
    const bool doclip = (c == 0);
    xinit(inc[c], mkcoef(vb[c], j0, doclip));            // j0 < NSTEP always
    tl[c][0][0] = inc[c].f[9]; tl[c][0][1] = inc[c].f[10]; tl[c][0][2] = inc[c].f[11];
    #pragma unroll
    for (int k = 1; k < 4; ++k){
      const int j = j0 + k;
      if (j < NSTEP) xstep(inc[c], mkcoef(vb[c], j, doclip));
      tl[c][k][0] = inc[c].f[9]; tl[c][k][1] = inc[c].f[10]; tl[c][k][2] = inc[c].f[11];
    }
  }

  // ---- wave-level inclusive scan (Hillis-Steele, non-commutative) ----
  #pragma unroll
  for (int off = 1; off < 64; off <<= 1){
    Xf o[2];
    #pragma unroll
    for (int c = 0; c < 2; ++c)
      #pragma unroll
      for (int i = 0; i < 12; ++i) o[c].f[i] = __shfl_up(inc[c].f[i], off);
    if (ln >= off){
      inc[0] = xcombine(o[0], inc[0]);
      inc[1] = xcombine(o[1], inc[1]);
    }
  }
  if (ln == 63){
    #pragma unroll
    for (int c = 0; c < 2; ++c)
      #pragma unroll
      for (int i = 0; i < 12; ++i) xch[c][wv][i] = inc[c].f[i];
  }
  Xf ex[2];
  #pragma unroll
  for (int c = 0; c < 2; ++c)
    #pragma unroll
    for (int i = 0; i < 12; ++i) ex[c].f[i] = __shfl_up(inc[c].f[i], 1);
  if (ln == 0){ ex[0] = xident(); ex[1] = xident(); }
  __syncthreads();

  // ---- inter-wave exclusive prefix ----
  Xf E[2];
  #pragma unroll
  for (int c = 0; c < 2; ++c){
    if (wv == 0){ E[c] = ex[c]; }
    else {
      Xf P;
      #pragma unroll
      for (int i = 0; i < 12; ++i) P.f[i] = xch[c][0][i];
      for (int w2 = 1; w2 < wv; ++w2){
        Xf Q;
        #pragma unroll
        for (int i = 0; i < 12; ++i) Q.f[i] = xch[c][w2][i];
        P = xcombine(P, Q);
      }
      E[c] = xcombine(P, ex[c]);
    }
  }

  // ---- fold (F0, a2) into prefix: G = F0*E.M ; G.t = a2 + F0*E.t ----
  float acc = 0.0f;
  Xf G[2];
  float a1x[2], a2x[2], a2y[2];
  #pragma unroll
  for (int c = 0; c < 2; ++c){
    float rb0 = vb[c][3064], rd0 = vb[c][2042], rb1 = vb[c][3065];
    if (c == 0){ rb0 = clip1(rb0); rd0 = clip1(rd0); rb1 = clip1(rb1); }
    const float bl0 = fmaf(rb0, 1.05f, 1.95f);
    const float d0  = fmaf(rd0, 1.75f, 3.25f);
    const float b1  = fmaf(rb1, 1.05f, 1.95f);
    float ct0 = (bl0*bl0 + b1*b1 - d0*d0) * frcp(2.0f*bl0*b1);
    ct0 = fminf(fmaxf(ct0, -1.0f + EPSF), 1.0f - EPSF);
    const float st0 = sqrtf(fmaxf(1.0f - ct0*ct0, 0.0f));
    a1x[c] = bl0;
    a2x[c] = bl0 - b1*ct0;
    a2y[c] = b1*st0;
    const Xf& Ec = E[c];
    Xf Gg;
    Gg.f[0] = -ct0*Ec.f[0] - st0*Ec.f[3];
    Gg.f[1] = -ct0*Ec.f[1] - st0*Ec.f[4];
    Gg.f[2] = -ct0*Ec.f[2] - st0*Ec.f[5];
    Gg.f[3] =  st0*Ec.f[0] - ct0*Ec.f[3];
    Gg.f[4] =  st0*Ec.f[1] - ct0*Ec.f[4];
    Gg.f[5] =  st0*Ec.f[2] - ct0*Ec.f[5];
    Gg.f[6] = Ec.f[6]; Gg.f[7] = Ec.f[7]; Gg.f[8] = Ec.f[8];
    Gg.f[9]  = a2x[c] - ct0*Ec.f[9] - st0*Ec.f[10];
    Gg.f[10] = a2y[c] + st0*Ec.f[9] - ct0*Ec.f[10];
    Gg.f[11] = Ec.f[11];
    G[c] = Gg;
  }
  if (tid == 0){
    const float dx = a1x[0] - a1x[1];   // a1 differs only in x
    const float dy = a2x[0] - a2x[1];
    const float dz = a2y[0] - a2y[1];   // a2 differs in x,y (z=0); a0 diff = 0
    acc = dx*dx + dy*dy + dz*dz;
  }

  // ---- phase 3: d_k = G.t + G.M * t_local(k), accumulate diff^2 ----
  #pragma unroll
  for (int k = 0; k < 4; ++k){
    const int j = j0 + k;
    if (j < NSTEP){
      float p[2][3];
      #pragma unroll
      for (int c = 0; c < 2; ++c){
        const float tx = tl[c][k][0], ty = tl[c][k][1], tz = tl[c][k][2];
        p[c][0] = G[c].f[9]  + G[c].f[0]*tx + G[c].f[1]*ty + G[c].f[2]*tz;
        p[c][1] = G[c].f[10] + G[c].f[3]*tx + G[c].f[4]*ty + G[c].f[5]*tz;
        p[c][2] = G[c].f[11] + G[c].f[6]*tx + G[c].f[7]*ty + G[c].f[8]*tz;
      }
      const float dx = p[0][0] - p[1][0];
      const float dy = p[0][1] - p[1][1];
      const float dz = p[0][2] - p[1][2];
      acc = fmaf(dx, dx, acc);
      acc = fmaf(dy, dy, acc);
      acc = fmaf(dz, dz, acc);
    }
  }

  // ---- reduce + atomic ----
  #pragma unroll
  for (int off = 32; off > 0; off >>= 1) acc += __shfl_down(acc, off);
  if (ln == 0) atomicAdd(out, acc * INVMEAN);
}

extern "C" void kernel_launch(void* const* d_in, const int* in_sizes, int n_in,
                              void* d_out, int out_size, void* d_ws, size_t ws_size,
                              hipStream_t stream) {
  const float* pred = (const float*)d_in[0];
  const float* targ = (const float*)d_in[1];
  float* out = (float*)d_out;

  hipMemsetAsync(d_out, 0, sizeof(float), stream);
  rmsd_kernel<<<NROW, 256, 0, stream>>>(pred, targ, out);
}

// Round 4
// 130.417 us; speedup vs baseline: 9.4001x; 1.5210x over previous
//
#include <hip/hip_runtime.h>

// rmsdLoss via associative affine scan — one wave per chain.
// Step j (j=0..1020) is the rigid map  p -> p + F*(l*what_j) ; F -> F*R_j  with
//   what_j = (-ct, st*cc, st*sc)  (unit),  l = bl[2+j],
//   R_j columns: [ what | (-st, -ct*cc, -ct*sc) | (0, -sc, cc) ].
// Chunk elements (M,t) combine as (Ma*Mb, ta + Ma*tb).
// Block = 128 threads = 2 waves: wave0 = pred (clipped), wave1 = targ.
// Lane ln owns steps [16*ln, 16*ln+16); 6-level in-wave shuffle scan gives the
// exclusive prefix (no inter-wave scan). Positions d_k = G.t + G.M * t_local(k),
// G = fold(F0, a2, E). Pred positions cross to wave1 through 12 KB LDS.

#define LROW  4087
#define NSTEP 1021
#define NROW  2048
#define CHUNK 16
#define EPSF  1e-6f
#define INVMEAN (1.0f / (2048.0f * 1024.0f * 3.0f))

__device__ __forceinline__ float frcp(float x){ return __builtin_amdgcn_rcpf(x); }

struct Xf { float f[12]; };  // f[0..8] = M row-major, f[9..11] = t

__device__ __forceinline__ Xf xident(){
  Xf X;
  X.f[0]=1.f; X.f[1]=0.f; X.f[2]=0.f;
  X.f[3]=0.f; X.f[4]=1.f; X.f[5]=0.f;
  X.f[6]=0.f; X.f[7]=0.f; X.f[8]=1.f;
  X.f[9]=0.f; X.f[10]=0.f; X.f[11]=0.f;
  return X;
}

// A applied first, then B:  (Ma*Mb, ta + Ma*tb)
__device__ __forceinline__ Xf xcombine(const Xf& A, const Xf& B){
  Xf C;
  #pragma unroll
  for (int r = 0; r < 3; ++r){
    const float a0 = A.f[3*r], a1 = A.f[3*r+1], a2 = A.f[3*r+2];
    C.f[3*r]   = a0*B.f[0] + a1*B.f[3] + a2*B.f[6];
    C.f[3*r+1] = a0*B.f[1] + a1*B.f[4] + a2*B.f[7];
    C.f[3*r+2] = a0*B.f[2] + a1*B.f[5] + a2*B.f[8];
    C.f[9+r]   = A.f[9+r] + a0*B.f[9] + a1*B.f[10] + a2*B.f[11];
  }
  return C;
}

struct Coef { float l, ct, st, cc, sc; };

// running (M,t) <- combine(running, step): t += M*(l*what) ; M <- M*R
__device__ __forceinline__ void xstep(Xf& X, const Coef& k){
  const float w0 = -k.ct, w1 = k.st*k.cc, w2 = k.st*k.sc;   // unit what
  const float ux = X.f[0]*w0 + X.f[1]*w1 + X.f[2]*w2;
  const float uy = X.f[3]*w0 + X.f[4]*w1 + X.f[5]*w2;
  const float uz = X.f[6]*w0 + X.f[7]*w1 + X.f[8]*w2;
  X.f[9]  = fmaf(k.l, ux, X.f[9]);
  X.f[10] = fmaf(k.l, uy, X.f[10]);
  X.f[11] = fmaf(k.l, uz, X.f[11]);
  const float a = -k.st, b = -k.ct*k.cc, d = -k.ct*k.sc;
  const float n1x = a*X.f[0] + b*X.f[1] + d*X.f[2];
  const float n1y = a*X.f[3] + b*X.f[4] + d*X.f[5];
  const float n1z = a*X.f[6] + b*X.f[7] + d*X.f[8];
  const float n2x = -k.sc*X.f[1] + k.cc*X.f[2];
  const float n2y = -k.sc*X.f[4] + k.cc*X.f[5];
  const float n2z = -k.sc*X.f[7] + k.cc*X.f[8];
  X.f[0] = ux; X.f[1] = n1x; X.f[2] = n2x;
  X.f[3] = uy; X.f[4] = n1y; X.f[5] = n2y;
  X.f[6] = uz; X.f[7] = n1z; X.f[8] = n2z;
}

// X = first step directly (identity composed with step)
__device__ __forceinline__ void xinit(Xf& X, const Coef& k){
  X.f[0] = -k.ct;      X.f[1] = -k.st;      X.f[2] = 0.f;
  X.f[3] = k.st*k.cc;  X.f[4] = -k.ct*k.cc; X.f[5] = -k.sc;
  X.f[6] = k.st*k.sc;  X.f[7] = -k.ct*k.sc; X.f[8] = k.cc;
  X.f[9] = k.l*X.f[0]; X.f[10] = k.l*X.f[3]; X.f[11] = k.l*X.f[6];
}

__device__ __forceinline__ Coef mkcoef(float s0, float s1, float rd, float rb1, float rb2){
  const float d  = fmaf(rd,  1.75f, 3.25f);
  const float b1 = fmaf(rb1, 1.05f, 1.95f);
  const float b2 = fmaf(rb2, 1.05f, 1.95f);
  float ct = (b1*b1 + b2*b2 - d*d) * frcp(2.0f*b1*b2);
  ct = fminf(fmaxf(ct, -1.0f + EPSF), 1.0f - EPSF);
  const float st = sqrtf(fmaxf(1.0f - ct*ct, 0.0f));
  const float r2 = s0*s0 + s1*s1;
  const bool ok = r2 > 1e-36f;
  const float ir = ok ? frcp(sqrtf(r2)) : 0.0f;
  Coef K;
  K.sc = s0 * ir;
  K.cc = ok ? s1 * ir : 1.0f;
  K.ct = ct; K.st = st; K.l = b2;
  return K;
}

__global__ void __launch_bounds__(128, 2)
rmsd_kernel(const float* __restrict__ pred, const float* __restrict__ targ,
            float* __restrict__ out){
  __shared__ float pos[64][CHUNK][3];   // pred positions (12 KB)
  __shared__ float ini[3];              // pred a1x, a2x, a2y

  const int row = blockIdx.x;
  const int tid = threadIdx.x;
  const int ln  = tid & 63;
  const int wv  = tid >> 6;      // 0 = pred, 1 = targ
  const int j0  = ln * CHUNK;

  const float* __restrict__ v = (wv == 0 ? pred : targ) + (size_t)row * LROW;
  const float lim = (wv == 0) ? 1.0f : 1e30f;   // reference clips pred only

  // ---- load all raw inputs for this lane's chunk (one vmcnt batch) ----
  float rsc[2*CHUNK], rdv[CHUNK], rbv[CHUNK+1];
  #pragma unroll
  for (int i = 0; i < 2*CHUNK; ++i)
    rsc[i] = fminf(fmaxf(v[2*j0 + i], -lim), lim);
  #pragma unroll
  for (int i = 0; i < CHUNK; ++i){
    int idx = 2043 + j0 + i; idx = idx > 3063 ? 3063 : idx;   // lane-63 tail clamp
    rdv[i] = fminf(fmaxf(v[idx], -lim), lim);
  }
  #pragma unroll
  for (int i = 0; i < CHUNK+1; ++i){
    int idx = 3065 + j0 + i; idx = idx > 4086 ? 4086 : idx;   // lane-63 tail clamp (OOB guard)
    rbv[i] = fminf(fmaxf(v[idx], -lim), lim);
  }

  // ---- phase 1: per-lane chunk compose, snapshot local-prefix translations ----
  Xf X;
  float tl[CHUNK][3];
  xinit(X, mkcoef(rsc[0], rsc[1], rdv[0], rbv[0], rbv[1]));
  tl[0][0] = X.f[9]; tl[0][1] = X.f[10]; tl[0][2] = X.f[11];
  #pragma unroll
  for (int k = 1; k < CHUNK; ++k){
    if (j0 + k < NSTEP)
      xstep(X, mkcoef(rsc[2*k], rsc[2*k+1], rdv[k], rbv[k], rbv[k+1]));
    tl[k][0] = X.f[9]; tl[k][1] = X.f[10]; tl[k][2] = X.f[11];
  }

  // ---- in-wave inclusive scan (Hillis-Steele, non-commutative) ----
  #pragma unroll
  for (int off = 1; off < 64; off <<= 1){
    Xf o;
    #pragma unroll
    for (int i = 0; i < 12; ++i) o.f[i] = __shfl_up(X.f[i], off);
    if (ln >= off) X = xcombine(o, X);
  }
  // exclusive prefix
  Xf E;
  #pragma unroll
  for (int i = 0; i < 12; ++i) E.f[i] = __shfl_up(X.f[i], 1);
  if (ln == 0) E = xident();

  // ---- fold (F0, a2): G = F0*E.M ; G.t = a2 + F0*E.t ----
  float rb0 = fminf(fmaxf(v[3064], -lim), lim);
  float rd0 = fminf(fmaxf(v[2042], -lim), lim);
  float rb1 = fminf(fmaxf(v[3065], -lim), lim);
  const float bl0 = fmaf(rb0, 1.05f, 1.95f);
  const float d0  = fmaf(rd0, 1.75f, 3.25f);
  const float b1  = fmaf(rb1, 1.05f, 1.95f);
  float ct0 = (bl0*bl0 + b1*b1 - d0*d0) * frcp(2.0f*bl0*b1);
  ct0 = fminf(fmaxf(ct0, -1.0f + EPSF), 1.0f - EPSF);
  const float st0 = sqrtf(fmaxf(1.0f - ct0*ct0, 0.0f));
  const float a1x = bl0;
  const float a2x = bl0 - b1*ct0;
  const float a2y = b1*st0;

  Xf G;   // F0 rows: (-ct0,-st0,0),(st0,-ct0,0),(0,0,1)
  G.f[0] = -ct0*E.f[0] - st0*E.f[3];
  G.f[1] = -ct0*E.f[1] - st0*E.f[4];
  G.f[2] = -ct0*E.f[2] - st0*E.f[5];
  G.f[3] =  st0*E.f[0] - ct0*E.f[3];
  G.f[4] =  st0*E.f[1] - ct0*E.f[4];
  G.f[5] =  st0*E.f[2] - ct0*E.f[5];
  G.f[6] = E.f[6]; G.f[7] = E.f[7]; G.f[8] = E.f[8];
  G.f[9]  = a2x - ct0*E.f[9] - st0*E.f[10];
  G.f[10] = a2y + st0*E.f[9] - ct0*E.f[10];
  G.f[11] = E.f[11];

  // ---- positions d_k = G.t + G.M * t_local(k) ----
  float p[CHUNK][3];
  #pragma unroll
  for (int k = 0; k < CHUNK; ++k){
    const float tx = tl[k][0], ty = tl[k][1], tz = tl[k][2];
    p[k][0] = G.f[9]  + G.f[0]*tx + G.f[1]*ty + G.f[2]*tz;
    p[k][1] = G.f[10] + G.f[3]*tx + G.f[4]*ty + G.f[5]*tz;
    p[k][2] = G.f[11] + G.f[6]*tx + G.f[7]*ty + G.f[8]*tz;
  }

  // ---- exchange pred positions, diff on targ wave ----
  if (wv == 0){
    #pragma unroll
    for (int k = 0; k < CHUNK; ++k){
      pos[ln][k][0] = p[k][0];
      pos[ln][k][1] = p[k][1];
      pos[ln][k][2] = p[k][2];
    }
    if (ln == 0){ ini[0] = a1x; ini[1] = a2x; ini[2] = a2y; }
  }
  __syncthreads();

  if (wv == 1){
    float acc = 0.0f;
    if (ln == 0){
      const float dx = ini[0] - a1x;   // a1 differs only in x; a0 diff = 0
      const float dy = ini[1] - a2x;   // a2 differs in x,y (z = 0)
      const float dz = ini[2] - a2y;
      acc = dx*dx + dy*dy + dz*dz;
    }
    #pragma unroll
    for (int k = 0; k < CHUNK; ++k){
      if (j0 + k < NSTEP){
        const float dx = pos[ln][k][0] - p[k][0];
        const float dy = pos[ln][k][1] - p[k][1];
        const float dz = pos[ln][k][2] - p[k][2];
        acc = fmaf(dx, dx, acc);
        acc = fmaf(dy, dy, acc);
        acc = fmaf(dz, dz, acc);
      }
    }
    #pragma unroll
    for (int off = 32; off > 0; off >>= 1) acc += __shfl_down(acc, off);
    if (ln == 0) atomicAdd(out, acc * INVMEAN);
  }
}

extern "C" void kernel_launch(void* const* d_in, const int* in_sizes, int n_in,
                              void* d_out, int out_size, void* d_ws, size_t ws_size,
                              hipStream_t stream) {
  const float* pred = (const float*)d_in[0];
  const float* targ = (const float*)d_in[1];
  float* out = (float*)d_out;

  hipMemsetAsync(d_out, 0, sizeof(float), stream);
  rmsd_kernel<<<NROW, 128, 0, stream>>>(pred, targ, out);
}

// Round 5
// 126.662 us; speedup vs baseline: 9.6787x; 1.0296x over previous
//
#include <hip/hip_runtime.h>

// rmsdLoss via associative affine scan — one wave per chain, LDS-staged inputs.
// Step j (j=0..1020) is the rigid map  p -> p + F*(l*what_j) ; F -> F*R_j  with
//   what_j = (-ct, st*cc, st*sc)  (unit),  l = bl[2+j],
//   R_j columns: [ what | (-st, -ct*cc, -ct*sc) | (0, -sc, cc) ].
// Chunk elements (M,t) combine as (Ma*Mb, ta + Ma*tb).
// Block = 128 threads = 2 waves: wave0 = pred (clipped), wave1 = targ.
// Each wave stages its row coalesced into a stride-33 padded LDS image
// (bank = (group + off) % 32 -> at most the free 2-way aliasing), then lane ln
// owns steps [16*ln, 16*ln+16) reading coefficients from LDS. 6-level in-wave
// shuffle scan gives the exclusive prefix; d_k = G.t + G.M * t_local(k).
// Pred positions cross to wave1 by REUSING wave0's staging buffer (dead by then).

#define LROW  4087
#define NSTEP 1021
#define NROW  2048
#define CHUNK 16
#define NGRP  132            // ceil(4087/32) = 128 groups; 132*33 > 4224 safe
#define SSZ   (128 * 33)     // 4224 floats per wave image
#define EPSF  1e-6f
#define INVMEAN (1.0f / (2048.0f * 1024.0f * 3.0f))

__device__ __forceinline__ float frcp(float x){ return __builtin_amdgcn_rcpf(x); }

struct Xf { float f[12]; };  // f[0..8] = M row-major, f[9..11] = t

__device__ __forceinline__ Xf xident(){
  Xf X;
  X.f[0]=1.f; X.f[1]=0.f; X.f[2]=0.f;
  X.f[3]=0.f; X.f[4]=1.f; X.f[5]=0.f;
  X.f[6]=0.f; X.f[7]=0.f; X.f[8]=1.f;
  X.f[9]=0.f; X.f[10]=0.f; X.f[11]=0.f;
  return X;
}

// A applied first, then B:  (Ma*Mb, ta + Ma*tb)
__device__ __forceinline__ Xf xcombine(const Xf& A, const Xf& B){
  Xf C;
  #pragma unroll
  for (int r = 0; r < 3; ++r){
    const float a0 = A.f[3*r], a1 = A.f[3*r+1], a2 = A.f[3*r+2];
    C.f[3*r]   = a0*B.f[0] + a1*B.f[3] + a2*B.f[6];
    C.f[3*r+1] = a0*B.f[1] + a1*B.f[4] + a2*B.f[7];
    C.f[3*r+2] = a0*B.f[2] + a1*B.f[5] + a2*B.f[8];
    C.f[9+r]   = A.f[9+r] + a0*B.f[9] + a1*B.f[10] + a2*B.f[11];
  }
  return C;
}

struct Coef { float l, ct, st, cc, sc; };

// running (M,t) <- combine(running, step): t += M*(l*what) ; M <- M*R
__device__ __forceinline__ void xstep(Xf& X, const Coef& k){
  const float w0 = -k.ct, w1 = k.st*k.cc, w2 = k.st*k.sc;   // unit what
  const float ux = X.f[0]*w0 + X.f[1]*w1 + X.f[2]*w2;
  const float uy = X.f[3]*w0 + X.f[4]*w1 + X.f[5]*w2;
  const float uz = X.f[6]*w0 + X.f[7]*w1 + X.f[8]*w2;
  X.f[9]  = fmaf(k.l, ux, X.f[9]);
  X.f[10] = fmaf(k.l, uy, X.f[10]);
  X.f[11] = fmaf(k.l, uz, X.f[11]);
  const float a = -k.st, b = -k.ct*k.cc, d = -k.ct*k.sc;
  const float n1x = a*X.f[0] + b*X.f[1] + d*X.f[2];
  const float n1y = a*X.f[3] + b*X.f[4] + d*X.f[5];
  const float n1z = a*X.f[6] + b*X.f[7] + d*X.f[8];
  const float n2x = -k.sc*X.f[1] + k.cc*X.f[2];
  const float n2y = -k.sc*X.f[4] + k.cc*X.f[5];
  const float n2z = -k.sc*X.f[7] + k.cc*X.f[8];
  X.f[0] = ux; X.f[1] = n1x; X.f[2] = n2x;
  X.f[3] = uy; X.f[4] = n1y; X.f[5] = n2y;
  X.f[6] = uz; X.f[7] = n1z; X.f[8] = n2z;
}

// X = first step directly (identity composed with step)
__device__ __forceinline__ void xinit(Xf& X, const Coef& k){
  X.f[0] = -k.ct;      X.f[1] = -k.st;      X.f[2] = 0.f;
  X.f[3] = k.st*k.cc;  X.f[4] = -k.ct*k.cc; X.f[5] = -k.sc;
  X.f[6] = k.st*k.sc;  X.f[7] = -k.ct*k.sc; X.f[8] = k.cc;
  X.f[9] = k.l*X.f[0]; X.f[10] = k.l*X.f[3]; X.f[11] = k.l*X.f[6];
}

__device__ __forceinline__ Coef mkcoef(float s0, float s1, float rd, float rb1, float rb2){
  const float d  = fmaf(rd,  1.75f, 3.25f);
  const float b1 = fmaf(rb1, 1.05f, 1.95f);
  const float b2 = fmaf(rb2, 1.05f, 1.95f);
  float ct = (b1*b1 + b2*b2 - d*d) * frcp(2.0f*b1*b2);
  ct = fminf(fmaxf(ct, -1.0f + EPSF), 1.0f - EPSF);
  const float st = sqrtf(fmaxf(1.0f - ct*ct, 0.0f));
  const float r2 = s0*s0 + s1*s1;
  const bool ok = r2 > 1e-36f;
  const float ir = ok ? frcp(sqrtf(r2)) : 0.0f;
  Coef K;
  K.sc = s0 * ir;
  K.cc = ok ? s1 * ir : 1.0f;
  K.ct = ct; K.st = st; K.l = b2;
  return K;
}

__global__ void __launch_bounds__(128, 2)
rmsd_kernel(const float* __restrict__ pred, const float* __restrict__ targ,
            float* __restrict__ out){
  __shared__ float sbuf[2][SSZ];   // 33.8 KB: padded row images (stride 33 per 32-group)
  __shared__ float ini[3];         // pred a1x, a2x, a2y

  const int row = blockIdx.x;
  const int tid = threadIdx.x;
  const int ln  = tid & 63;
  const int wv  = tid >> 6;      // 0 = pred, 1 = targ
  const int j0  = ln * CHUNK;

  const float* __restrict__ v = (wv == 0 ? pred : targ) + (size_t)row * LROW;
  float* __restrict__ S = sbuf[wv];
  const float lim = (wv == 0) ? 1.0f : 1e30f;   // reference clips pred only

  // ---- stage row coalesced into padded LDS image (clip at staging) ----
  #pragma unroll 4
  for (int k = ln; k < LROW; k += 64){
    const float x = fminf(fmaxf(v[k], -lim), lim);
    S[(k >> 5) * 33 + (k & 31)] = x;
  }
  __syncthreads();

  auto rdS = [&](int idx) -> float { return S[(idx >> 5) * 33 + (idx & 31)]; };

  // ---- phase 1: per-lane chunk compose, snapshot local-prefix translations ----
  Xf X;
  float tl[CHUNK][3];
  xinit(X, mkcoef(rdS(2*j0), rdS(2*j0+1), rdS(2043+j0), rdS(3065+j0), rdS(3066+j0)));
  tl[0][0] = X.f[9]; tl[0][1] = X.f[10]; tl[0][2] = X.f[11];
  #pragma unroll
  for (int k = 1; k < CHUNK; ++k){
    const int j = j0 + k;
    if (j < NSTEP)
      xstep(X, mkcoef(rdS(2*j), rdS(2*j+1), rdS(2043+j), rdS(3065+j), rdS(3066+j)));
    tl[k][0] = X.f[9]; tl[k][1] = X.f[10]; tl[k][2] = X.f[11];
  }

  // ---- in-wave inclusive scan (Hillis-Steele, non-commutative) ----
  #pragma unroll
  for (int off = 1; off < 64; off <<= 1){
    Xf o;
    #pragma unroll
    for (int i = 0; i < 12; ++i) o.f[i] = __shfl_up(X.f[i], off);
    if (ln >= off) X = xcombine(o, X);
  }
  // exclusive prefix
  Xf E;
  #pragma unroll
  for (int i = 0; i < 12; ++i) E.f[i] = __shfl_up(X.f[i], 1);
  if (ln == 0) E = xident();

  // ---- fold (F0, a2): G = F0*E.M ; G.t = a2 + F0*E.t ----
  const float rb0 = rdS(3064);
  const float rd0 = rdS(2042);
  const float rb1 = rdS(3065);
  const float bl0 = fmaf(rb0, 1.05f, 1.95f);
  const float d0  = fmaf(rd0, 1.75f, 3.25f);
  const float b1  = fmaf(rb1, 1.05f, 1.95f);
  float ct0 = (bl0*bl0 + b1*b1 - d0*d0) * frcp(2.0f*bl0*b1);
  ct0 = fminf(fmaxf(ct0, -1.0f + EPSF), 1.0f - EPSF);
  const float st0 = sqrtf(fmaxf(1.0f - ct0*ct0, 0.0f));
  const float a1x = bl0;
  const float a2x = bl0 - b1*ct0;
  const float a2y = b1*st0;

  Xf G;   // F0 rows: (-ct0,-st0,0),(st0,-ct0,0),(0,0,1)
  G.f[0] = -ct0*E.f[0] - st0*E.f[3];
  G.f[1] = -ct0*E.f[1] - st0*E.f[4];
  G.f[2] = -ct0*E.f[2] - st0*E.f[5];
  G.f[3] =  st0*E.f[0] - ct0*E.f[3];
  G.f[4] =  st0*E.f[1] - ct0*E.f[4];
  G.f[5] =  st0*E.f[2] - ct0*E.f[5];
  G.f[6] = E.f[6]; G.f[7] = E.f[7]; G.f[8] = E.f[8];
  G.f[9]  = a2x - ct0*E.f[9] - st0*E.f[10];
  G.f[10] = a2y + st0*E.f[9] - ct0*E.f[10];
  G.f[11] = E.f[11];

  // ---- positions d_k = G.t + G.M * t_local(k) ----
  float p[CHUNK][3];
  #pragma unroll
  for (int k = 0; k < CHUNK; ++k){
    const float tx = tl[k][0], ty = tl[k][1], tz = tl[k][2];
    p[k][0] = G.f[9]  + G.f[0]*tx + G.f[1]*ty + G.f[2]*tz;
    p[k][1] = G.f[10] + G.f[3]*tx + G.f[4]*ty + G.f[5]*tz;
    p[k][2] = G.f[11] + G.f[6]*tx + G.f[7]*ty + G.f[8]*tz;
  }

  // ---- exchange pred positions (reuse wave0's dead staging buffer) ----
  float (*pos)[CHUNK][3] = (float (*)[CHUNK][3])(&sbuf[0][0]);  // 12 KB < 16.9 KB
  if (wv == 0){
    #pragma unroll
    for (int k = 0; k < CHUNK; ++k){
      pos[ln][k][0] = p[k][0];
      pos[ln][k][1] = p[k][1];
      pos[ln][k][2] = p[k][2];
    }
    if (ln == 0){ ini[0] = a1x; ini[1] = a2x; ini[2] = a2y; }
  }
  __syncthreads();

  if (wv == 1){
    float acc = 0.0f;
    if (ln == 0){
      const float dx = ini[0] - a1x;   // a1 differs only in x; a0 diff = 0
      const float dy = ini[1] - a2x;   // a2 differs in x,y (z = 0)
      const float dz = ini[2] - a2y;
      acc = dx*dx + dy*dy + dz*dz;
    }
    #pragma unroll
    for (int k = 0; k < CHUNK; ++k){
      if (j0 + k < NSTEP){
        const float dx = pos[ln][k][0] - p[k][0];
        const float dy = pos[ln][k][1] - p[k][1];
        const float dz = pos[ln][k][2] - p[k][2];
        acc = fmaf(dx, dx, acc);
        acc = fmaf(dy, dy, acc);
        acc = fmaf(dz, dz, acc);
      }
    }
    #pragma unroll
    for (int off = 32; off > 0; off >>= 1) acc += __shfl_down(acc, off);
    if (ln == 0) atomicAdd(out, acc * INVMEAN);
  }
}

extern "C" void kernel_launch(void* const* d_in, const int* in_sizes, int n_in,
                              void* d_out, int out_size, void* d_ws, size_t ws_size,
                              hipStream_t stream) {
  const float* pred = (const float*)d_in[0];
  const float* targ = (const float*)d_in[1];
  float* out = (float*)d_out;

  hipMemsetAsync(d_out, 0, sizeof(float), stream);
  rmsd_kernel<<<NROW, 128, 0, stream>>>(pred, targ, out);
}